// Round 5
// baseline (321.710 us; speedup 1.0000x reference)
//
#include <hip/hip_runtime.h>

// LaterallyConnectedLayer: B=16, NUM_FM=64, N=4, NF=256, H=W=32, KS=5. All fp32.
// Derived math:
//   w1t[i][o][k]  = minmax5x5( K[i][o] )                (i-major layout)
//   wsum2[g][o][k]= sum_n w1t[64n+g][o][k]
//   score[b,o]    = (sum-1024*min)/(max-min) over conv_same(A[b,:],wsum[o,:])*S[o]
//   n*[b,f]       = argmax_n score[b,64n+f]  (first-max ties; const A-term drops)
//   out[b,f]      = (1/64) sum_g conv_same(A[b,g], w1[64n*_f+f][64n*_g+g])

#define NFM 64
#define NMX 4
#define NFC 256
#define HW 1024
#define KK 25

// --- kprep: normalize K -> w1t (coalesced), accumulate wsum2 ----------------
__global__ __launch_bounds__(256) void kprep(const float* __restrict__ K,
                                             float* __restrict__ w1t,
                                             float* __restrict__ wsum2) {
    __shared__ __align__(16) float buf[64 * KK];
    int g = blockIdx.x & 63, o0 = (blockIdx.x >> 6) * 64;
    int t = threadIdx.x;
    float wacc[KK];
#pragma unroll
    for (int k = 0; k < KK; ++k) wacc[k] = 0.f;

    for (int n = 0; n < NMX; ++n) {
        int i = n * NFM + g;
        const float4* src = (const float4*)(K + (i * NFC + o0) * KK);
        __syncthreads();
        ((float4*)buf)[t] = src[t];
        if (t < 144) ((float4*)buf)[t + 256] = src[t + 256];
        __syncthreads();
        if (t < 64) {
            float v[KK];
            float mn = 1e30f, mx = -1e30f;
#pragma unroll
            for (int k = 0; k < KK; ++k) {
                v[k] = buf[t * KK + k];
                mn = fminf(mn, v[k]);
                mx = fmaxf(mx, v[k]);
            }
            float d = mx - mn;
            float r = d > 0.f ? 1.f / d : 0.f;
#pragma unroll
            for (int k = 0; k < KK; ++k) {
                float nv = (v[k] - mn) * r;
                buf[t * KK + k] = nv;
                wacc[k] += nv;
            }
        }
        __syncthreads();
        float4* dst = (float4*)(w1t + (i * NFC + o0) * KK);
        dst[t] = ((float4*)buf)[t];
        if (t < 144) dst[t + 256] = ((float4*)buf)[t + 256];
    }
    __syncthreads();
    if (t < 64) {
#pragma unroll
        for (int k = 0; k < KK; ++k) buf[t * KK + k] = wacc[k];
    }
    __syncthreads();
    float4* dst = (float4*)(wsum2 + (g * NFC + o0) * KK);
    dst[t] = ((float4*)buf)[t];
    if (t < 144) dst[t + 256] = ((float4*)buf)[t + 256];
}

// --- kscore: grid (32,16). Wave = o-pair x full image, WAVE-PRIVATE LDS -----
// No __syncthreads in the main loop: each wave stages A into its own buffer;
// per-wave DS ops are in-order, wave_barrier() pins compiler ordering.
__global__ __launch_bounds__(256) void kscore(const float* __restrict__ A,
                                              const float* __restrict__ wsum2,
                                              const float* __restrict__ S,
                                              float* __restrict__ score) {
    __shared__ __align__(16) float pa[4][36 * 36 + 4];   // per-wave buffer
    int t = threadIdx.x, b = blockIdx.y;
    int wv = __builtin_amdgcn_readfirstlane(t >> 6);
    int lane = t & 63;
    int ob = blockIdx.x * 8 + wv * 2;
    int xb = (lane & 7) * 4;
    int yb = (lane >> 3) * 4;
    float* buf = pa[wv];

    for (int i = lane; i < 36 * 36; i += 64) buf[i] = 0.f;
    __builtin_amdgcn_wave_barrier();

    const float* Ab = A + b * NFM * HW;
    float* sdst[4];
#pragma unroll
    for (int j = 0; j < 4; ++j) {
        int p = lane + 64 * j;                      // f4 index in 32x32 image
        sdst[j] = &buf[((p >> 3) + 2) * 36 + (p & 7) * 4 + 2];
    }
    {
        const float4* src = (const float4*)Ab;      // g = 0
#pragma unroll
        for (int j = 0; j < 4; ++j) {
            float4 q = src[lane + 64 * j];
            *(float2*)&sdst[j][0] = make_float2(q.x, q.y);
            *(float2*)&sdst[j][2] = make_float2(q.z, q.w);
        }
    }
    __builtin_amdgcn_wave_barrier();

    float acc0[16], acc1[16];
#pragma unroll
    for (int j = 0; j < 16; ++j) { acc0[j] = 0.f; acc1[j] = 0.f; }

    for (int g = 0; g < NFM; ++g) {
        float4 qn[4];
        bool more = (g + 1) < NFM;
        if (more) {
            const float4* src = (const float4*)(Ab + (g + 1) * HW);
#pragma unroll
            for (int j = 0; j < 4; ++j) qn[j] = src[lane + 64 * j];
        }

        const float* wg = wsum2 + (g * NFC + ob) * KK;   // uniform -> s_load
        float w0[KK], w1r[KK];
#pragma unroll
        for (int k = 0; k < KK; ++k) { w0[k] = wg[k]; w1r[k] = wg[KK + k]; }

#pragma unroll
        for (int r = 0; r < 8; ++r) {
            float4 a0 = *(const float4*)&buf[(yb + r) * 36 + xb];
            float4 a1 = *(const float4*)&buf[(yb + r) * 36 + xb + 4];
            float a[8] = {a0.x, a0.y, a0.z, a0.w, a1.x, a1.y, a1.z, a1.w};
#pragma unroll
            for (int py = 0; py < 4; ++py) {
                int u = r - py;
                if (u >= 0 && u < 5) {
#pragma unroll
                    for (int v = 0; v < 5; ++v) {
                        float wa = w0[u * 5 + v], wb = w1r[u * 5 + v];
#pragma unroll
                        for (int px = 0; px < 4; ++px) {
                            acc0[py * 4 + px] = fmaf(a[px + v], wa, acc0[py * 4 + px]);
                            acc1[py * 4 + px] = fmaf(a[px + v], wb, acc1[py * 4 + px]);
                        }
                    }
                }
            }
        }
        __builtin_amdgcn_wave_barrier();
        if (more) {
#pragma unroll
            for (int j = 0; j < 4; ++j) {
                *(float2*)&sdst[j][0] = make_float2(qn[j].x, qn[j].y);
                *(float2*)&sdst[j][2] = make_float2(qn[j].z, qn[j].w);
            }
        }
        __builtin_amdgcn_wave_barrier();
    }

#pragma unroll
    for (int oo = 0; oo < 2; ++oo) {
        const float* ac = oo ? acc1 : acc0;
        float scale = S[ob + oo] * (1.f / 64.f);
        float lmn = 1e30f, lmx = -1e30f, lsum = 0.f;
#pragma unroll
        for (int j = 0; j < 16; ++j) {
            float vv = ac[j] * scale;
            lmn = fminf(lmn, vv);
            lmx = fmaxf(lmx, vv);
            lsum += vv;
        }
#pragma unroll
        for (int m = 1; m < 64; m <<= 1) {
            lmn = fminf(lmn, __shfl_xor(lmn, m, 64));
            lmx = fmaxf(lmx, __shfl_xor(lmx, m, 64));
            lsum += __shfl_xor(lsum, m, 64);
        }
        if (lane == 0) {
            float d = lmx - lmn;
            score[b * NFC + ob + oo] = d > 0.f ? (lsum - 1024.f * lmn) / d : 0.f;
        }
    }
}

// --- kout: grid (16,2,16). Wave = 1 f x half image, wave-private LDS --------
__global__ __launch_bounds__(256) void kout(const float* __restrict__ A,
                                            const float* __restrict__ w1t,
                                            const float* __restrict__ score,
                                            float* __restrict__ out) {
    __shared__ __align__(16) float pa[4][20 * 36 + 4];
    __shared__ float scl[NFC];
    __shared__ int igL[NFM];
    int t = threadIdx.x, z = blockIdx.y, b = blockIdx.z;

    scl[t] = score[b * NFC + t];
    __syncthreads();
    if (t < 64) {
        float best = scl[t];
        int bi = 0;
#pragma unroll
        for (int n = 1; n < NMX; ++n) {
            float v = scl[n * NFM + t];
            if (v > best) { best = v; bi = n; }
        }
        igL[t] = bi * NFM + t;
    }
    __syncthreads();   // igL ready; no more block barriers after this

    int wv = __builtin_amdgcn_readfirstlane(t >> 6);
    int lane = t & 63;
    int f = blockIdx.x * 4 + wv;
    int o = __builtin_amdgcn_readfirstlane(igL[f]);
    int y0 = z * 16;
    int xb = (lane & 7) * 4;
    int yb = (lane >> 3) * 2;
    float* buf = pa[wv];

    for (int i = lane; i < 20 * 36; i += 64) buf[i] = 0.f;
    __builtin_amdgcn_wave_barrier();

    const float* Ab = A + b * NFM * HW;
    // staging slots: f4 idx p = lane, lane+64, lane+128(lane<32); pa row = p>>3
    int p0 = lane, p1 = lane + 64, p2 = lane + 128;
    int r0 = p0 >> 3, r1 = p1 >> 3, r2 = p2 >> 3;
    int gy0 = y0 - 2 + r0, gy1 = y0 - 2 + r1, gy2 = y0 - 2 + r2;
    bool v0 = (gy0 >= 0) && (gy0 < 32);
    bool v1 = (gy1 >= 0) && (gy1 < 32);
    bool v2 = (lane < 32) && (gy2 >= 0) && (gy2 < 32);
    float* d0 = &buf[r0 * 36 + (p0 & 7) * 4 + 2];
    float* d1 = &buf[r1 * 36 + (p1 & 7) * 4 + 2];
    float* d2 = &buf[r2 * 36 + (p2 & 7) * 4 + 2];
    int c0 = (p0 & 7) * 4, c1 = (p1 & 7) * 4, c2 = (p2 & 7) * 4;

    {
        if (v0) { float4 q = *(const float4*)(Ab + gy0 * 32 + c0);
                  *(float2*)&d0[0] = make_float2(q.x, q.y);
                  *(float2*)&d0[2] = make_float2(q.z, q.w); }
        if (v1) { float4 q = *(const float4*)(Ab + gy1 * 32 + c1);
                  *(float2*)&d1[0] = make_float2(q.x, q.y);
                  *(float2*)&d1[2] = make_float2(q.z, q.w); }
        if (v2) { float4 q = *(const float4*)(Ab + gy2 * 32 + c2);
                  *(float2*)&d2[0] = make_float2(q.x, q.y);
                  *(float2*)&d2[2] = make_float2(q.z, q.w); }
    }
    __builtin_amdgcn_wave_barrier();

    float acc[8];
#pragma unroll
    for (int j = 0; j < 8; ++j) acc[j] = 0.f;

    // weight register pipeline
    float wn[KK];
    {
        int ig0 = __builtin_amdgcn_readfirstlane(igL[0]);
        const float* wp = w1t + (ig0 * NFC + o) * KK;
#pragma unroll
        for (int k = 0; k < KK; ++k) wn[k] = wp[k];
    }

    for (int g = 0; g < NFM; ++g) {
        float4 q0, q1, q2;
        bool more = (g + 1) < NFM;
        if (more) {
            const float* Ag = Ab + (g + 1) * HW;
            if (v0) q0 = *(const float4*)(Ag + gy0 * 32 + c0);
            if (v1) q1 = *(const float4*)(Ag + gy1 * 32 + c1);
            if (v2) q2 = *(const float4*)(Ag + gy2 * 32 + c2);
        }

        float wc[KK];
#pragma unroll
        for (int k = 0; k < KK; ++k) wc[k] = wn[k];
        if (more) {
            int ign = __builtin_amdgcn_readfirstlane(igL[g + 1]);
            const float* wp = w1t + (ign * NFC + o) * KK;
#pragma unroll
            for (int k = 0; k < KK; ++k) wn[k] = wp[k];
        }

#pragma unroll
        for (int r = 0; r < 6; ++r) {
            float4 a0 = *(const float4*)&buf[(yb + r) * 36 + xb];
            float4 a1 = *(const float4*)&buf[(yb + r) * 36 + xb + 4];
            float a[8] = {a0.x, a0.y, a0.z, a0.w, a1.x, a1.y, a1.z, a1.w};
#pragma unroll
            for (int py = 0; py < 2; ++py) {
                int u = r - py;
                if (u >= 0 && u < 5) {
#pragma unroll
                    for (int v = 0; v < 5; ++v) {
                        float wvv = wc[u * 5 + v];
#pragma unroll
                        for (int px = 0; px < 4; ++px)
                            acc[py * 4 + px] = fmaf(a[px + v], wvv, acc[py * 4 + px]);
                    }
                }
            }
        }
        __builtin_amdgcn_wave_barrier();
        if (more) {
            if (v0) { *(float2*)&d0[0] = make_float2(q0.x, q0.y);
                      *(float2*)&d0[2] = make_float2(q0.z, q0.w); }
            if (v1) { *(float2*)&d1[0] = make_float2(q1.x, q1.y);
                      *(float2*)&d1[2] = make_float2(q1.z, q1.w); }
            if (v2) { *(float2*)&d2[0] = make_float2(q2.x, q2.y);
                      *(float2*)&d2[2] = make_float2(q2.z, q2.w); }
        }
        __builtin_amdgcn_wave_barrier();
    }

    float* ob = out + (b * NFM + f) * HW;
#pragma unroll
    for (int py = 0; py < 2; ++py) {
        float4 q;
        q.x = acc[py * 4 + 0] * (1.f / 64.f);
        q.y = acc[py * 4 + 1] * (1.f / 64.f);
        q.z = acc[py * 4 + 2] * (1.f / 64.f);
        q.w = acc[py * 4 + 3] * (1.f / 64.f);
        *(float4*)&ob[(y0 + yb + py) * 32 + xb] = q;
    }
}

extern "C" void kernel_launch(void* const* d_in, const int* in_sizes, int n_in,
                              void* d_out, int out_size, void* d_ws, size_t ws_size,
                              hipStream_t stream) {
    const float* A = (const float*)d_in[0];   // (16,64,32,32) f32
    const float* K = (const float*)d_in[1];   // (256,256,5,5) f32
    const float* S = (const float*)d_in[2];   // (256,) f32
    float* out = (float*)d_out;               // (16,64,32,32) f32

    char* ws = (char*)d_ws;
    float* w1t   = (float*)ws;                        // 6,553,600 B
    float* wsum2 = (float*)(ws + 6553600);            // 1,638,400 B
    float* score = (float*)(ws + 6553600 + 1638400);  // 16,384 B

    kprep<<<dim3(256), dim3(256), 0, stream>>>(K, w1t, wsum2);
    kscore<<<dim3(32, 16), dim3(256), 0, stream>>>(A, wsum2, S, score);
    kout<<<dim3(16, 2, 16), dim3(256), 0, stream>>>(A, w1t, score, out);
}